// Round 17
// baseline (179.109 us; speedup 1.0000x reference)
//
#include <hip/hip_runtime.h>

#define HDIM 256
#define TDIM 256
#define VOUT 10
#define BC   8     // batch rows per block -> 256 blocks, every CU busy

typedef _Float16 f16x8 __attribute__((ext_vector_type(8)));
typedef float    f32x4 __attribute__((ext_vector_type(4)));

// Weights pre-scaled by 2*log2(e): MFMA/fma outputs are exp2 arguments.
// tanh(a) = 1 - 2/(2^(u) + 1), u = 2*log2e*a
#define SCALE 2.8853900817779268f

__device__ __forceinline__ float tanh_u(float u) {
    float e = exp2f(u);                      // single v_exp_f32 (2^x native)
    return 1.0f - 2.0f * __builtin_amdgcn_rcpf(e + 1.0f);
}

// pack two f32 -> 2x f16 (RTZ) as a 32-bit word (v_cvt_pkrtz_f16_f32)
__device__ __forceinline__ unsigned pkrtz_u32(float a, float b) {
    auto v = __builtin_amdgcn_cvt_pkrtz(a, b);   // __fp16 ext_vector(2)
    union { decltype(v) h; unsigned u; } cvt;
    cvt.h = v;
    return cvt.u;
}

// v17 = v16 with (1) dedup reverted to rg-pair split (two b32 writes at
// banks 4rn+2(g&1)+hi -> conflict-free; v16's mt-split b64 write was 2-way
// bank-conflicted) and (2) scale = 2*log2e folded into Wh/bh/We/be so every
// tanh uses exp2 directly (kills the v_mul inside __expf; 8 fewer VALU/step).
__global__ __launch_bounds__(512, 1) void rnn_fwd_v17(
    const float* __restrict__ x,    // [B, T]
    const float* __restrict__ We,   // [H]
    const float* __restrict__ be,   // [H]
    const float* __restrict__ Wh,   // [H, H] (in, out)
    const float* __restrict__ bh,   // [H]
    const float* __restrict__ Wo,   // [H, V]
    const float* __restrict__ bo,   // [V]
    float* __restrict__ out)        // [B, V]
{
    __shared__ __align__(16) char vraw[2][BC * HDIM * 2];   // 2 x 4 KB f16
    __shared__ float x_lds[BC][TDIM + 2];                   // 8.3 KB
    __shared__ float h_fin[BC][HDIM + 1];                   // 8.2 KB

    const int tid = threadIdx.x;
    const int l   = tid & 63;
    const int w   = tid >> 6;       // wave 0..7 -> h-cols [32w, 32w+32)
    const int n   = l & 15;         // MFMA N slot
    const int rn  = n & 7;          // batch row (n>=8 aliases)
    const int hi  = n >> 3;         // rg-pair selector (dedup split)
    const int g   = l >> 4;
    const int r0  = blockIdx.x * BC;

    // ---- stage x (coalesced) ----
    for (int k = tid; k < BC * TDIM; k += 512) {
        int r = k >> 8, t = k & 255;
        x_lds[r][t] = x[(r0 + r) * TDIM + t];
    }

    // ---- W_h -> register fragments, scaled by 2*log2e ----
    // wfrag[mt][kt][e] = SCALE * Wh[(kt*32+g*8+e)*H + 32w+16mt+n]
    f16x8 wfrag[2][8];
    #pragma unroll
    for (int mt = 0; mt < 2; ++mt) {
        const int col = 32 * w + 16 * mt + n;
        #pragma unroll
        for (int kt = 0; kt < 8; ++kt) {
            #pragma unroll
            for (int e = 0; e < 8; ++e)
                wfrag[mt][kt][e] = (_Float16)(SCALE * Wh[(kt * 32 + g * 8 + e) * HDIM + col]);
        }
    }

    // bh (xSCALE) as C-init vectors (hcol = 32w+16mt+4g+rg)
    f32x4 bh0, bh1;
    #pragma unroll
    for (int rg = 0; rg < 4; ++rg) {
        bh0[rg] = SCALE * bh[32 * w + 4 * g + rg];
        bh1[rg] = SCALE * bh[32 * w + 16 + 4 * g + rg];
    }

    // ---- own-hcol We/be (xSCALE): lane owns hcols 32w+16mt+4g+2hi+{0,1} ----
    float WeO[2][2], beO[2][2];
    #pragma unroll
    for (int mt = 0; mt < 2; ++mt) {
        const int hc = 32 * w + 16 * mt + 4 * g + 2 * hi;
        WeO[mt][0] = SCALE * We[hc];     beO[mt][0] = SCALE * be[hc];
        WeO[mt][1] = SCALE * We[hc + 1]; beO[mt][1] = SCALE * be[hc + 1];
    }

    // ---- LDS addresses (chunk-major; rg-pair write banks 4rn+2(g&1)+hi: CF) ----
    const int base_r = g * 128 + rn * 16;              // bfrag: + kt*512
    int addr_w[2];
    #pragma unroll
    for (int mt = 0; mt < 2; ++mt)
        addr_w[mt] = (4 * w + 2 * mt + (g >> 1)) * 128 + rn * 16 + (g & 1) * 8 + hi * 4;

    __syncthreads();

    // ---- v(0) = tanh(x[:,0]*We + be)  (h0 = 0) ----
    {
        const float xv = x_lds[rn][0];
        #pragma unroll
        for (int mt = 0; mt < 2; ++mt) {
            const float s0 = tanh_u(fmaf(xv, WeO[mt][0], beO[mt][0]));
            const float s1 = tanh_u(fmaf(xv, WeO[mt][1], beO[mt][1]));
            *(unsigned*)(&vraw[0][0] + addr_w[mt]) = pkrtz_u32(s0, s1);
        }
    }
    __syncthreads();

    int cur = 0;
    #pragma unroll 2
    for (int t = 0; t < TDIM - 1; ++t) {
        const char* vr = &vraw[cur][0];
        char*       vw = &vraw[cur ^ 1][0];

        // reads: x first (in-order lgkm), then bfrag burst
        const float xv = x_lds[rn][t + 1];
        f16x8 bfrag[8];
        #pragma unroll
        for (int kt = 0; kt < 8; ++kt)
            bfrag[kt] = *(const f16x8*)(vr + base_r + kt * 512);

        // ipp = 1 + inp-tanh = 2 - 2*rcp(2^u + 1)
        float ipp[2][2];
        #pragma unroll
        for (int mt = 0; mt < 2; ++mt) {
            #pragma unroll
            for (int j = 0; j < 2; ++j) {
                const float u = fmaf(xv, WeO[mt][j], beO[mt][j]);
                const float e = exp2f(u);
                const float r = __builtin_amdgcn_rcpf(e + 1.0f);
                ipp[mt][j] = fmaf(-2.0f, r, 2.0f);
            }
        }

        // 4 independent 4-deep MFMA chains; C-init folds SCALE*bh / 0
        const f32x4 zero = {0.f, 0.f, 0.f, 0.f};
        f32x4 accE0 = __builtin_amdgcn_mfma_f32_16x16x32_f16(wfrag[0][0], bfrag[0], bh0,  0, 0, 0);
        f32x4 accE1 = __builtin_amdgcn_mfma_f32_16x16x32_f16(wfrag[1][0], bfrag[0], bh1,  0, 0, 0);
        f32x4 accO0 = __builtin_amdgcn_mfma_f32_16x16x32_f16(wfrag[0][1], bfrag[1], zero, 0, 0, 0);
        f32x4 accO1 = __builtin_amdgcn_mfma_f32_16x16x32_f16(wfrag[1][1], bfrag[1], zero, 0, 0, 0);
        #pragma unroll
        for (int kp = 1; kp < 4; ++kp) {
            accE0 = __builtin_amdgcn_mfma_f32_16x16x32_f16(wfrag[0][2 * kp],     bfrag[2 * kp],     accE0, 0, 0, 0);
            accE1 = __builtin_amdgcn_mfma_f32_16x16x32_f16(wfrag[1][2 * kp],     bfrag[2 * kp],     accE1, 0, 0, 0);
            accO0 = __builtin_amdgcn_mfma_f32_16x16x32_f16(wfrag[0][2 * kp + 1], bfrag[2 * kp + 1], accO0, 0, 0, 0);
            accO1 = __builtin_amdgcn_mfma_f32_16x16x32_f16(wfrag[1][2 * kp + 1], bfrag[2 * kp + 1], accO1, 0, 0, 0);
        }

        // tails (rg-pair dedup: lane handles rg {2hi, 2hi+1} of both mts)
        {
            const float a0 = (hi ? accE0[2] : accE0[0]) + (hi ? accO0[2] : accO0[0]);
            const float a1 = (hi ? accE0[3] : accE0[1]) + (hi ? accO0[3] : accO0[1]);
            const float r0v = __builtin_amdgcn_rcpf(exp2f(a0) + 1.0f);
            const float r1v = __builtin_amdgcn_rcpf(exp2f(a1) + 1.0f);
            const float s0 = fmaf(-2.0f, r0v, ipp[0][0]);
            const float s1 = fmaf(-2.0f, r1v, ipp[0][1]);
            *(unsigned*)(vw + addr_w[0]) = pkrtz_u32(s0, s1);
        }
        {
            const float a0 = (hi ? accE1[2] : accE1[0]) + (hi ? accO1[2] : accO1[0]);
            const float a1 = (hi ? accE1[3] : accE1[1]) + (hi ? accO1[3] : accO1[1]);
            const float r0v = __builtin_amdgcn_rcpf(exp2f(a0) + 1.0f);
            const float r1v = __builtin_amdgcn_rcpf(exp2f(a1) + 1.0f);
            const float s0 = fmaf(-2.0f, r0v, ipp[1][0]);
            const float s1 = fmaf(-2.0f, r1v, ipp[1][1]);
            *(unsigned*)(vw + addr_w[1]) = pkrtz_u32(s0, s1);
        }
        cur ^= 1;
        __syncthreads();
    }

    // ---- peeled final step: h_fin = tanh(acc) ----
    {
        const char* vr = &vraw[cur][0];
        f16x8 bfrag[8];
        #pragma unroll
        for (int kt = 0; kt < 8; ++kt)
            bfrag[kt] = *(const f16x8*)(vr + base_r + kt * 512);

        const f32x4 zero = {0.f, 0.f, 0.f, 0.f};
        f32x4 accE0 = __builtin_amdgcn_mfma_f32_16x16x32_f16(wfrag[0][0], bfrag[0], bh0,  0, 0, 0);
        f32x4 accE1 = __builtin_amdgcn_mfma_f32_16x16x32_f16(wfrag[1][0], bfrag[0], bh1,  0, 0, 0);
        f32x4 accO0 = __builtin_amdgcn_mfma_f32_16x16x32_f16(wfrag[0][1], bfrag[1], zero, 0, 0, 0);
        f32x4 accO1 = __builtin_amdgcn_mfma_f32_16x16x32_f16(wfrag[1][1], bfrag[1], zero, 0, 0, 0);
        #pragma unroll
        for (int kp = 1; kp < 4; ++kp) {
            accE0 = __builtin_amdgcn_mfma_f32_16x16x32_f16(wfrag[0][2 * kp],     bfrag[2 * kp],     accE0, 0, 0, 0);
            accE1 = __builtin_amdgcn_mfma_f32_16x16x32_f16(wfrag[1][2 * kp],     bfrag[2 * kp],     accE1, 0, 0, 0);
            accO0 = __builtin_amdgcn_mfma_f32_16x16x32_f16(wfrag[0][2 * kp + 1], bfrag[2 * kp + 1], accO0, 0, 0, 0);
            accO1 = __builtin_amdgcn_mfma_f32_16x16x32_f16(wfrag[1][2 * kp + 1], bfrag[2 * kp + 1], accO1, 0, 0, 0);
        }
        {
            const float a0 = (hi ? accE0[2] : accE0[0]) + (hi ? accO0[2] : accO0[0]);
            const float a1 = (hi ? accE0[3] : accE0[1]) + (hi ? accO0[3] : accO0[1]);
            const int hc = 32 * w + 4 * g + 2 * hi;
            h_fin[rn][hc + 0] = tanh_u(a0);
            h_fin[rn][hc + 1] = tanh_u(a1);
        }
        {
            const float a0 = (hi ? accE1[2] : accE1[0]) + (hi ? accO1[2] : accO1[0]);
            const float a1 = (hi ? accE1[3] : accE1[1]) + (hi ? accO1[3] : accO1[1]);
            const int hc = 32 * w + 16 + 4 * g + 2 * hi;
            h_fin[rn][hc + 0] = tanh_u(a0);
            h_fin[rn][hc + 1] = tanh_u(a1);
        }
    }
    __syncthreads();

    // ---- epilogue: out[r][v] = bo[v] + sum_i h[r][i] * Wo[i*V+v] ----
    if (tid < BC * VOUT) {
        const int r = tid / VOUT, vc = tid - r * VOUT;
        float sacc = bo[vc];
        #pragma unroll 8
        for (int i = 0; i < HDIM; ++i)
            sacc = fmaf(h_fin[r][i], Wo[i * VOUT + vc], sacc);
        out[(r0 + r) * VOUT + vc] = sacc;
    }
}

extern "C" void kernel_launch(void* const* d_in, const int* in_sizes, int n_in,
                              void* d_out, int out_size, void* d_ws, size_t ws_size,
                              hipStream_t stream) {
    const float* x  = (const float*)d_in[0];
    const float* We = (const float*)d_in[1];
    const float* be = (const float*)d_in[2];
    const float* Wh = (const float*)d_in[3];
    const float* bh = (const float*)d_in[4];
    const float* Wo = (const float*)d_in[5];
    const float* bo = (const float*)d_in[6];
    float* out = (float*)d_out;

    const int B = in_sizes[0] / TDIM;      // 2048
    const int nblocks = B / BC;            // 256

    rnn_fwd_v17<<<nblocks, 512, 0, stream>>>(x, We, be, Wh, bh, Wo, bo, out);
}

// Round 18
// 144.278 us; speedup vs baseline: 1.2414x; 1.2414x over previous
//
#include <hip/hip_runtime.h>

#define HDIM 256
#define TDIM 256
#define VOUT 10
#define BC   8     // batch rows per block -> 256 blocks, every CU busy

typedef _Float16 f16x8 __attribute__((ext_vector_type(8)));
typedef float    f32x4 __attribute__((ext_vector_type(4)));

// Weights pre-scaled by 2*log2(e): MFMA/fma outputs are exp2 arguments.
// tanh(a) = 1 - 2/(2^u + 1), u = 2*log2e*a
#define SCALE 2.8853900817779268f

// native v_exp_f32 (2^x). exp2f() is the precise OCML path (10+ extra VALU) --
// measured 20% regression in v17. Guard for safety.
#if __has_builtin(__builtin_amdgcn_exp2f)
#define EXP2(x) __builtin_amdgcn_exp2f(x)
#else
#define EXP2(x) __expf(0.6931471805599453f * (x))
#endif

// pack two f32 -> 2x f16 (RTZ) as a 32-bit word (v_cvt_pkrtz_f16_f32)
__device__ __forceinline__ unsigned pkrtz_u32(float a, float b) {
    auto v = __builtin_amdgcn_cvt_pkrtz(a, b);   // __fp16 ext_vector(2)
    union { decltype(v) h; unsigned u; } cvt;
    cvt.h = v;
    return cvt.u;
}

__device__ __forceinline__ float tanh_u(float u) {
    float e = EXP2(u);
    return 1.0f - 2.0f * __builtin_amdgcn_rcpf(e + 1.0f);
}

// v18 = v16 structure + rg-pair conflict-free writes (v10/v17 style) +
// SCALE=2*log2e fold with NATIVE exp2 builtin (v17's exp2f was the OCML
// precise path -- the whole regression). Unroll 2, peeled last step, pkrtz.
__global__ __launch_bounds__(512, 1) void rnn_fwd_v18(
    const float* __restrict__ x,    // [B, T]
    const float* __restrict__ We,   // [H]
    const float* __restrict__ be,   // [H]
    const float* __restrict__ Wh,   // [H, H] (in, out)
    const float* __restrict__ bh,   // [H]
    const float* __restrict__ Wo,   // [H, V]
    const float* __restrict__ bo,   // [V]
    float* __restrict__ out)        // [B, V]
{
    __shared__ __align__(16) char vraw[2][BC * HDIM * 2];   // 2 x 4 KB f16
    __shared__ float x_lds[BC][TDIM + 2];                   // 8.3 KB
    __shared__ float h_fin[BC][HDIM + 1];                   // 8.2 KB

    const int tid = threadIdx.x;
    const int l   = tid & 63;
    const int w   = tid >> 6;       // wave 0..7 -> h-cols [32w, 32w+32)
    const int n   = l & 15;         // MFMA N slot
    const int rn  = n & 7;          // batch row (n>=8 aliases)
    const int hi  = n >> 3;         // rg-pair selector (dedup split)
    const int g   = l >> 4;
    const int r0  = blockIdx.x * BC;

    // ---- stage x (coalesced) ----
    for (int k = tid; k < BC * TDIM; k += 512) {
        int r = k >> 8, t = k & 255;
        x_lds[r][t] = x[(r0 + r) * TDIM + t];
    }

    // ---- W_h -> register fragments, scaled by 2*log2e ----
    f16x8 wfrag[2][8];
    #pragma unroll
    for (int mt = 0; mt < 2; ++mt) {
        const int col = 32 * w + 16 * mt + n;
        #pragma unroll
        for (int kt = 0; kt < 8; ++kt) {
            #pragma unroll
            for (int e = 0; e < 8; ++e)
                wfrag[mt][kt][e] = (_Float16)(SCALE * Wh[(kt * 32 + g * 8 + e) * HDIM + col]);
        }
    }

    // bh (xSCALE) as C-init vectors (hcol = 32w+16mt+4g+rg)
    f32x4 bh0, bh1;
    #pragma unroll
    for (int rg = 0; rg < 4; ++rg) {
        bh0[rg] = SCALE * bh[32 * w + 4 * g + rg];
        bh1[rg] = SCALE * bh[32 * w + 16 + 4 * g + rg];
    }

    // ---- own-hcol We/be (xSCALE): lane owns hcols 32w+16mt+4g+2hi+{0,1} ----
    float WeO[2][2], beO[2][2];
    #pragma unroll
    for (int mt = 0; mt < 2; ++mt) {
        const int hc = 32 * w + 16 * mt + 4 * g + 2 * hi;
        WeO[mt][0] = SCALE * We[hc];     beO[mt][0] = SCALE * be[hc];
        WeO[mt][1] = SCALE * We[hc + 1]; beO[mt][1] = SCALE * be[hc + 1];
    }

    // ---- LDS addresses (chunk-major; rg-pair writes -> banks 4rn+2(g&1)+hi, CF) ----
    const int base_r = g * 128 + rn * 16;              // bfrag: + kt*512
    int addr_w[2];
    #pragma unroll
    for (int mt = 0; mt < 2; ++mt)
        addr_w[mt] = (4 * w + 2 * mt + (g >> 1)) * 128 + rn * 16 + (g & 1) * 8 + hi * 4;

    __syncthreads();

    // ---- v(0) = tanh(x[:,0]*We + be)  (h0 = 0) ----
    {
        const float xv = x_lds[rn][0];
        #pragma unroll
        for (int mt = 0; mt < 2; ++mt) {
            const float s0 = tanh_u(fmaf(xv, WeO[mt][0], beO[mt][0]));
            const float s1 = tanh_u(fmaf(xv, WeO[mt][1], beO[mt][1]));
            *(unsigned*)(&vraw[0][0] + addr_w[mt]) = pkrtz_u32(s0, s1);
        }
    }
    __syncthreads();

    int cur = 0;
    #pragma unroll 2
    for (int t = 0; t < TDIM - 1; ++t) {
        const char* vr = &vraw[cur][0];
        char*       vw = &vraw[cur ^ 1][0];

        // reads: x first (in-order lgkm), then bfrag burst
        const float xv = x_lds[rn][t + 1];
        f16x8 bfrag[8];
        #pragma unroll
        for (int kt = 0; kt < 8; ++kt)
            bfrag[kt] = *(const f16x8*)(vr + base_r + kt * 512);

        // ipp = 1 + inp-tanh = 2 - 2*rcp(2^u + 1)
        float ipp[2][2];
        #pragma unroll
        for (int mt = 0; mt < 2; ++mt) {
            #pragma unroll
            for (int j = 0; j < 2; ++j) {
                const float u = fmaf(xv, WeO[mt][j], beO[mt][j]);
                const float e = EXP2(u);
                const float r = __builtin_amdgcn_rcpf(e + 1.0f);
                ipp[mt][j] = fmaf(-2.0f, r, 2.0f);
            }
        }

        // 4 independent 4-deep MFMA chains; C-init folds SCALE*bh / 0
        const f32x4 zero = {0.f, 0.f, 0.f, 0.f};
        f32x4 accE0 = __builtin_amdgcn_mfma_f32_16x16x32_f16(wfrag[0][0], bfrag[0], bh0,  0, 0, 0);
        f32x4 accE1 = __builtin_amdgcn_mfma_f32_16x16x32_f16(wfrag[1][0], bfrag[0], bh1,  0, 0, 0);
        f32x4 accO0 = __builtin_amdgcn_mfma_f32_16x16x32_f16(wfrag[0][1], bfrag[1], zero, 0, 0, 0);
        f32x4 accO1 = __builtin_amdgcn_mfma_f32_16x16x32_f16(wfrag[1][1], bfrag[1], zero, 0, 0, 0);
        #pragma unroll
        for (int kp = 1; kp < 4; ++kp) {
            accE0 = __builtin_amdgcn_mfma_f32_16x16x32_f16(wfrag[0][2 * kp],     bfrag[2 * kp],     accE0, 0, 0, 0);
            accE1 = __builtin_amdgcn_mfma_f32_16x16x32_f16(wfrag[1][2 * kp],     bfrag[2 * kp],     accE1, 0, 0, 0);
            accO0 = __builtin_amdgcn_mfma_f32_16x16x32_f16(wfrag[0][2 * kp + 1], bfrag[2 * kp + 1], accO0, 0, 0, 0);
            accO1 = __builtin_amdgcn_mfma_f32_16x16x32_f16(wfrag[1][2 * kp + 1], bfrag[2 * kp + 1], accO1, 0, 0, 0);
        }

        // tails (rg-pair dedup: lane handles rg {2hi, 2hi+1} of both mts)
        {
            const float a0 = (hi ? accE0[2] : accE0[0]) + (hi ? accO0[2] : accO0[0]);
            const float a1 = (hi ? accE0[3] : accE0[1]) + (hi ? accO0[3] : accO0[1]);
            const float r0v = __builtin_amdgcn_rcpf(EXP2(a0) + 1.0f);
            const float r1v = __builtin_amdgcn_rcpf(EXP2(a1) + 1.0f);
            const float s0 = fmaf(-2.0f, r0v, ipp[0][0]);
            const float s1 = fmaf(-2.0f, r1v, ipp[0][1]);
            *(unsigned*)(vw + addr_w[0]) = pkrtz_u32(s0, s1);
        }
        {
            const float a0 = (hi ? accE1[2] : accE1[0]) + (hi ? accO1[2] : accO1[0]);
            const float a1 = (hi ? accE1[3] : accE1[1]) + (hi ? accO1[3] : accO1[1]);
            const float r0v = __builtin_amdgcn_rcpf(EXP2(a0) + 1.0f);
            const float r1v = __builtin_amdgcn_rcpf(EXP2(a1) + 1.0f);
            const float s0 = fmaf(-2.0f, r0v, ipp[1][0]);
            const float s1 = fmaf(-2.0f, r1v, ipp[1][1]);
            *(unsigned*)(vw + addr_w[1]) = pkrtz_u32(s0, s1);
        }
        cur ^= 1;
        __syncthreads();
    }

    // ---- peeled final step: h_fin = tanh(acc) ----
    {
        const char* vr = &vraw[cur][0];
        f16x8 bfrag[8];
        #pragma unroll
        for (int kt = 0; kt < 8; ++kt)
            bfrag[kt] = *(const f16x8*)(vr + base_r + kt * 512);

        const f32x4 zero = {0.f, 0.f, 0.f, 0.f};
        f32x4 accE0 = __builtin_amdgcn_mfma_f32_16x16x32_f16(wfrag[0][0], bfrag[0], bh0,  0, 0, 0);
        f32x4 accE1 = __builtin_amdgcn_mfma_f32_16x16x32_f16(wfrag[1][0], bfrag[0], bh1,  0, 0, 0);
        f32x4 accO0 = __builtin_amdgcn_mfma_f32_16x16x32_f16(wfrag[0][1], bfrag[1], zero, 0, 0, 0);
        f32x4 accO1 = __builtin_amdgcn_mfma_f32_16x16x32_f16(wfrag[1][1], bfrag[1], zero, 0, 0, 0);
        #pragma unroll
        for (int kp = 1; kp < 4; ++kp) {
            accE0 = __builtin_amdgcn_mfma_f32_16x16x32_f16(wfrag[0][2 * kp],     bfrag[2 * kp],     accE0, 0, 0, 0);
            accE1 = __builtin_amdgcn_mfma_f32_16x16x32_f16(wfrag[1][2 * kp],     bfrag[2 * kp],     accE1, 0, 0, 0);
            accO0 = __builtin_amdgcn_mfma_f32_16x16x32_f16(wfrag[0][2 * kp + 1], bfrag[2 * kp + 1], accO0, 0, 0, 0);
            accO1 = __builtin_amdgcn_mfma_f32_16x16x32_f16(wfrag[1][2 * kp + 1], bfrag[2 * kp + 1], accO1, 0, 0, 0);
        }
        {
            const float a0 = (hi ? accE0[2] : accE0[0]) + (hi ? accO0[2] : accO0[0]);
            const float a1 = (hi ? accE0[3] : accE0[1]) + (hi ? accO0[3] : accO0[1]);
            const int hc = 32 * w + 4 * g + 2 * hi;
            h_fin[rn][hc + 0] = tanh_u(a0);
            h_fin[rn][hc + 1] = tanh_u(a1);
        }
        {
            const float a0 = (hi ? accE1[2] : accE1[0]) + (hi ? accO1[2] : accO1[0]);
            const float a1 = (hi ? accE1[3] : accE1[1]) + (hi ? accO1[3] : accO1[1]);
            const int hc = 32 * w + 16 + 4 * g + 2 * hi;
            h_fin[rn][hc + 0] = tanh_u(a0);
            h_fin[rn][hc + 1] = tanh_u(a1);
        }
    }
    __syncthreads();

    // ---- epilogue: out[r][v] = bo[v] + sum_i h[r][i] * Wo[i*V+v] ----
    if (tid < BC * VOUT) {
        const int r = tid / VOUT, vc = tid - r * VOUT;
        float sacc = bo[vc];
        #pragma unroll 8
        for (int i = 0; i < HDIM; ++i)
            sacc = fmaf(h_fin[r][i], Wo[i * VOUT + vc], sacc);
        out[(r0 + r) * VOUT + vc] = sacc;
    }
}

extern "C" void kernel_launch(void* const* d_in, const int* in_sizes, int n_in,
                              void* d_out, int out_size, void* d_ws, size_t ws_size,
                              hipStream_t stream) {
    const float* x  = (const float*)d_in[0];
    const float* We = (const float*)d_in[1];
    const float* be = (const float*)d_in[2];
    const float* Wh = (const float*)d_in[3];
    const float* bh = (const float*)d_in[4];
    const float* Wo = (const float*)d_in[5];
    const float* bo = (const float*)d_in[6];
    float* out = (float*)d_out;

    const int B = in_sizes[0] / TDIM;      // 2048
    const int nblocks = B / BC;            // 256

    rnn_fwd_v18<<<nblocks, 512, 0, stream>>>(x, We, be, Wh, bh, Wo, bo, out);
}